// Round 1
// baseline (264.000 us; speedup 1.0000x reference)
//
#include <hip/hip_runtime.h>

// HardMoE classifier: B=131072 rows, D=768, E=6 experts, L=2 labels.
// Per row: 6 gate dots + 12 expert dots (dense all-expert), argmax-select.
// Memory-bound: 403 MB X read, floor ~64us @ 6.3 TB/s.

#define BB 131072
#define DD 768
#define EE 6
#define LL 2
#define TILE_D 32           // floats per d-tile
#define NT (DD / TILE_D)    // 24 tiles
#define ROWS 256            // rows per block (= blockDim)

// async global->LDS, 16B per lane, dest = wave-uniform base + lane*16
#define GLOAD_LDS16(gsrc, ldst)                                                \
  __builtin_amdgcn_global_load_lds(                                            \
      (const __attribute__((address_space(1))) void*)(gsrc),                   \
      (__attribute__((address_space(3))) void*)(ldst), 16, 0, 0)

__global__ __launch_bounds__(256, 2)
void HardMoE_kernel(const float* __restrict__ X,   // [B][D]
                    const float* __restrict__ gw,  // [E][D]
                    const float* __restrict__ gb,  // [E]
                    const float* __restrict__ ew,  // [E][D][L]
                    const float* __restrict__ eb,  // [E][L]
                    float* __restrict__ out)       // [B][L]
{
  // double-buffered x tile: [2][256 rows][32 floats], 64 KB total.
  // content swizzle: lds[r][c4] (float4 slots c4=0..7) holds
  // X[row0+r][d0 + ((c4 ^ (r&7))<<2) .. +3]  -> read-side XOR kills the
  // 32-way stride-128B bank conflict (rule-21: swizzle source + read, LDS linear).
  __shared__ float lds[2][ROWS * TILE_D];

  const int tid  = threadIdx.x;
  const int lane = tid & 63;
  const int w    = tid >> 6;          // wave id 0..3
  const int row0 = blockIdx.x * ROWS;

  auto stage = [&](int buf, int tile) {
    const int d0  = tile * TILE_D;
    const int cls = lane >> 3;        // 0..7 (row-within-8 = swizzle class)
    const int c4  = lane & 7;         // float4 slot
#pragma unroll
    for (int i = 0; i < 8; ++i) {
      const int base_r = i * 32 + w * 8;          // wave-uniform, multiple of 8
      const int r      = base_r + cls;
      const float* src = X + (size_t)(row0 + r) * DD + d0 + ((c4 ^ cls) << 2);
      GLOAD_LDS16(src, &lds[buf][base_r * TILE_D]);
    }
  };

  float acc[18];                      // 0..5 gate, 6..17 expert (e*2+l)
#pragma unroll
  for (int j = 0; j < 18; ++j) acc[j] = 0.f;

  stage(0, 0);

  const int t     = tid;              // this thread's row within block
  const int cls_r = t & 7;

  for (int tile = 0; tile < NT; ++tile) {
    asm volatile("s_waitcnt vmcnt(0)" ::: "memory");  // own staging done
    __syncthreads();                                  // everyone's staging visible
    if (tile + 1 < NT) stage((tile + 1) & 1, tile + 1);  // writes the OTHER buffer

    const float* lrow = &lds[tile & 1][t * TILE_D];
    const int d0 = tile * TILE_D;
#pragma unroll
    for (int g = 0; g < 8; ++g) {
      const int slot  = g ^ cls_r;                        // un-swizzle
      const float4 xv = *(const float4*)(lrow + (slot << 2));
      const int d     = d0 + (g << 2);
#pragma unroll
      for (int k = 0; k < 6; ++k) {                       // gate: uniform -> s_load
        const float* wr = gw + k * DD + d;
        acc[k] += xv.x * wr[0] + xv.y * wr[1] + xv.z * wr[2] + xv.w * wr[3];
      }
#pragma unroll
      for (int e = 0; e < 6; ++e) {                       // experts: [d][l] interleaved
        const float* wr = ew + (size_t)(e * DD + d) * 2;
        acc[6 + 2 * e + 0] += xv.x * wr[0] + xv.y * wr[2] + xv.z * wr[4] + xv.w * wr[6];
        acc[6 + 2 * e + 1] += xv.x * wr[1] + xv.y * wr[3] + xv.z * wr[5] + xv.w * wr[7];
      }
    }
  }

  // argmax over gate logits (first-max tie rule, matches jnp.argmax)
  int   best = 0;
  float bv   = acc[0] + gb[0];
#pragma unroll
  for (int k = 1; k < 6; ++k) {
    const float v = acc[k] + gb[k];
    if (v > bv) { bv = v; best = k; }
  }
  // select routed expert output via cndmask chain (no dynamic reg indexing)
  float o0 = acc[6], o1 = acc[7];
#pragma unroll
  for (int e = 1; e < 6; ++e) {
    o0 = (best == e) ? acc[6 + 2 * e + 0] : o0;
    o1 = (best == e) ? acc[6 + 2 * e + 1] : o1;
  }
  o0 += eb[2 * best + 0];
  o1 += eb[2 * best + 1];

  ((float2*)out)[row0 + t] = make_float2(o0, o1);
}

extern "C" void kernel_launch(void* const* d_in, const int* in_sizes, int n_in,
                              void* d_out, int out_size, void* d_ws, size_t ws_size,
                              hipStream_t stream) {
  (void)in_sizes; (void)n_in; (void)d_ws; (void)ws_size; (void)out_size;
  const float* X  = (const float*)d_in[0];
  const float* gw = (const float*)d_in[1];
  const float* gb = (const float*)d_in[2];
  const float* ew = (const float*)d_in[3];
  const float* eb = (const float*)d_in[4];
  float* out = (float*)d_out;
  HardMoE_kernel<<<BB / ROWS, ROWS, 0, stream>>>(X, gw, gb, ew, eb, out);
}

// Round 2
// 168.992 us; speedup vs baseline: 1.5622x; 1.5622x over previous
//
#include <hip/hip_runtime.h>

// HardMoE classifier: B=131072, D=768, E=6, L=2.
// Per row: 18 dot-products of length 768 (6 gate + 12 dense expert), argmax-select.
// Memory-bound: 403 MB X read -> ~64us floor @ 6.3 TB/s.
// R2: weights staged in LDS once (kills per-tile s_load/L2 thrash),
//     triple-buffered X tiles with counted vmcnt(4) (2 stages in flight).

#define BB 131072
#define DD 768
#define ROWS 512            // rows per block = blockDim.x
#define TILE_D 16           // floats per d-tile
#define NT (DD / TILE_D)    // 48 tiles
#define NBUF 3
#define NW_GATE 4608        // 6*768 floats
#define NW_EXP  9216        // 6*768*2 floats

#define GLOAD_LDS16(gsrc, ldst)                                                \
  __builtin_amdgcn_global_load_lds(                                            \
      (const __attribute__((address_space(1))) void*)(gsrc),                   \
      (__attribute__((address_space(3))) void*)(ldst), 16, 0, 0)

#define WAITV4 asm volatile("s_waitcnt vmcnt(4)" ::: "memory")
#define WAITV0 asm volatile("s_waitcnt vmcnt(0)" ::: "memory")

__global__ __launch_bounds__(ROWS, 2)
void HardMoE_kernel(const float* __restrict__ X,   // [B][D]
                    const float* __restrict__ gw,  // [E][D]
                    const float* __restrict__ gb,  // [E]
                    const float* __restrict__ ew,  // [E][D][L]
                    const float* __restrict__ eb,  // [E][L]
                    float* __restrict__ out)       // [B][L]
{
  // weights: gw[6][768] at wlds[0..4607], ew[6][768][2] at wlds[4608..13823]
  __shared__ float wlds[NW_GATE + NW_EXP];              // 55296 B
  // x tiles, content-swizzled: row r slot c4 holds X[r][d0 + ((c4^(r&3))<<2)..+3]
  __shared__ float xlds[NBUF][ROWS * TILE_D];           // 3 x 32768 B

  const int tid  = threadIdx.x;
  const int lane = tid & 63;
  const int w    = tid >> 6;                            // wave 0..7
  const int row0 = blockIdx.x * ROWS;

  // ---- one-time weight preload (coalesced float4) ----
  {
    float4*       wd = (float4*)wlds;
    const float4* gs = (const float4*)gw;
    const float4* es = (const float4*)ew;
    for (int i = tid; i < NW_GATE / 4; i += ROWS) wd[i] = gs[i];
    for (int i = tid; i < NW_EXP / 4; i += ROWS)  wd[NW_GATE / 4 + i] = es[i];
  }
  asm volatile("" ::: "memory");  // keep stage() issue after the copy's loads

  auto stage = [&](int buf, int tile) {
    const int d0  = tile * TILE_D;
    const int cls = lane >> 2;                          // 0..15 row-in-16
    const int c4  = lane & 3;                           // float4 slot
#pragma unroll
    for (int i = 0; i < 4; ++i) {
      const int base_r = w * 64 + i * 16;               // wave-uniform
      const int r      = base_r + cls;
      const float* src = X + (size_t)(row0 + r) * DD + d0 + ((c4 ^ (cls & 3)) << 2);
      GLOAD_LDS16(src, &xlds[buf][base_r * TILE_D]);
    }
  };

  float acc[18];
#pragma unroll
  for (int j = 0; j < 18; ++j) acc[j] = 0.f;

  stage(0, 0);
  stage(1, 1);

  const float* gwL = wlds;
  const float* ewL = wlds + NW_GATE;
  const int t = tid;                                    // this thread's row

  for (int tile = 0; tile < NT; ++tile) {
    if (tile < NT - 1) { WAITV4; } else { WAITV0; }     // stage(tile) landed
    __syncthreads();                                    // visible to all waves
    if (tile + 2 < NT) stage((tile + 2) % NBUF, tile + 2);

    const float* lrow = &xlds[tile % NBUF][t * TILE_D];
    const int d0 = tile * TILE_D;
#pragma unroll
    for (int g = 0; g < 4; ++g) {
      const int s     = (g ^ t) & 3;                    // un-swizzle slot
      const float4 xv = *(const float4*)(lrow + (s << 2));
      const int d     = d0 + (g << 2);
#pragma unroll
      for (int k = 0; k < 6; ++k) {                     // gate (LDS broadcast)
        const float4 wv = *(const float4*)(gwL + k * DD + d);
        acc[k] += xv.x * wv.x + xv.y * wv.y + xv.z * wv.z + xv.w * wv.w;
      }
#pragma unroll
      for (int e = 0; e < 6; ++e) {                     // experts [d][l] pairs
        const float* wb = ewL + ((e * DD + d) << 1);
        const float4 a  = *(const float4*)(wb);
        const float4 b  = *(const float4*)(wb + 4);
        acc[6 + 2 * e + 0] += xv.x * a.x + xv.y * a.z + xv.z * b.x + xv.w * b.z;
        acc[6 + 2 * e + 1] += xv.x * a.y + xv.y * a.w + xv.z * b.y + xv.w * b.w;
      }
    }
  }

  // argmax over gate logits (first-max tie rule = jnp.argmax)
  int   best = 0;
  float bv   = acc[0] + gb[0];
#pragma unroll
  for (int k = 1; k < 6; ++k) {
    const float v = acc[k] + gb[k];
    if (v > bv) { bv = v; best = k; }
  }
  float o0 = acc[6], o1 = acc[7];
#pragma unroll
  for (int e = 1; e < 6; ++e) {
    o0 = (best == e) ? acc[6 + 2 * e + 0] : o0;
    o1 = (best == e) ? acc[6 + 2 * e + 1] : o1;
  }
  o0 += eb[2 * best + 0];
  o1 += eb[2 * best + 1];

  ((float2*)out)[row0 + t] = make_float2(o0, o1);
}

extern "C" void kernel_launch(void* const* d_in, const int* in_sizes, int n_in,
                              void* d_out, int out_size, void* d_ws, size_t ws_size,
                              hipStream_t stream) {
  (void)in_sizes; (void)n_in; (void)d_ws; (void)ws_size; (void)out_size;
  const float* X  = (const float*)d_in[0];
  const float* gw = (const float*)d_in[1];
  const float* gb = (const float*)d_in[2];
  const float* ew = (const float*)d_in[3];
  const float* eb = (const float*)d_in[4];
  float* out = (float*)d_out;
  HardMoE_kernel<<<BB / ROWS, ROWS, 0, stream>>>(X, gw, gb, eb ? ew : ew, eb, out);
}